// Round 4
// baseline (1129.554 us; speedup 1.0000x reference)
//
#include <hip/hip_runtime.h>

#define D_DIM 764
#define DP    768
#define BM    128
#define BN    128
#define BK    32

typedef __attribute__((ext_vector_type(8))) short bf16x8;
typedef __attribute__((ext_vector_type(8))) unsigned short u16x8;
typedef __attribute__((ext_vector_type(4))) float f32x4;

typedef __attribute__((address_space(3))) char lds_char;
typedef __attribute__((address_space(1))) const char g_char;

__device__ inline unsigned short f2bf(float f) {
    union { float f; unsigned u; } v; v.f = f;
    unsigned r = v.u + 0x7FFFu + ((v.u >> 16) & 1u);  // RNE
    return (unsigned short)(r >> 16);
}

// Mask (k < n), cast to bf16, pad to DP x DP. Layout: Wb[n][k] (BT form, K-contiguous).
__global__ void prep_w(const float* __restrict__ W, unsigned short* __restrict__ Wb) {
    int idx = blockIdx.x * blockDim.x + threadIdx.x;   // 0 .. DP*DP-1
    int n = idx / DP, k = idx - n * DP;
    float v = 0.0f;
    if (n < D_DIM && k < n) v = W[n * D_DIM + k];
    Wb[idx] = f2bf(v);
}

// v5: BK=32 occupancy build. LDS = As dbuf 16K + Bs tribuf 24K = 40 KB
// -> 4 blocks/CU = 32 waves (v4's 80 KB capped at 2 blocks/16 waves; all
// pipes were <30% busy => latency-bound, occupancy was the binding limit).
// At BK=32 rows are 64 B = 16 banks, so plain row-major fragment reads are
// bank-balanced (8 lanes per 4-bank group, 2-way = free) -> no swizzle at all;
// A ds_write and B global_load_lds dests are linear.
// Pipeline (v4 structure): prefetch distance 2 K-steps, 3 VMEM/wave/iter
// (2 A-loads + 1 B-DMA), counted s_waitcnt vmcnt(6) (never 0 mid-loop),
// ONE s_barrier per K-step. A reg sets statically named via unroll-2.
__global__ __launch_bounds__(512, 8) void fvsbn_gemm(
    const float* __restrict__ X,          // [65536, 764] fp32
    const unsigned short* __restrict__ Wb,// [768, 768] bf16 masked (BT layout)
    const float* __restrict__ bias,       // [764] fp32
    float* __restrict__ out)              // [65536, 764] fp32
{
    __shared__ __align__(16) unsigned short As[2][BM * BK]; // 16 KB
    __shared__ __align__(16) unsigned short Bs[3][BN * BK]; // 24 KB

    const int tid  = threadIdx.x;
    const int lane = tid & 63;
    const int wid  = tid >> 6;        // 0..7
    const int wm   = wid & 3;         // 32-row m-slice
    const int wn   = wid >> 2;        // 64-col n-slice
    const int quad = lane >> 4;
    const int l16  = lane & 15;

    // XCD-aware swizzle: 512 m-tiles x 6 n-tiles, contiguous m per XCD.
    const int bid = blockIdx.x;       // 0..3071
    const int xcd = bid & 7;
    const int j   = bid >> 3;         // 0..383
    const int nt  = j % 6;
    const int jm  = j / 6;            // 0..63
    const int mt  = jm * 8 + xcd;     // 0..511
    const int m0  = mt * BM;
    const int n0  = nt * BN;

    // Triangular skip: cols [n0, n0+127] need k <= n0+126.
    const int num_k = (n0 + BN) / BK;  // 4,8,12,16,20,24 (always even)

    // ---- A/B staging descriptors (plain row-major, no swizzle) ----
    // Position p = tid covers 128 rows x 4 chunks of 8 elems.
    const int ar = tid >> 2;          // 0..127
    const int ac = tid & 3;           // chunk
    const float* asrc = X + (size_t)(m0 + ar) * D_DIM + ac * 8;
    const int adst  = tid * 8;        // ushort index (= ar*32 + ac*8)
    const int hilim = D_DIM - 8 - ac * 8;  // hi float4 valid iff k0 <= hilim
    // B: 1 chunk per thread; DMA dest = wave-uniform base + lane*16 (linear).
    const unsigned short* bsrc = Wb + (size_t)(n0 + ar) * DP + ac * 8;
    const int bofs = wid * 64 * 16;   // wave-uniform byte base in a B buffer

    f32x4 acc[2][4];
#pragma unroll
    for (int mi = 0; mi < 2; ++mi)
#pragma unroll
        for (int ni = 0; ni < 4; ++ni) acc[mi][ni] = (f32x4){0.f, 0.f, 0.f, 0.f};

    // Two statically-named A register sets (even tiles -> set0, odd -> set1).
    float4 aLo0, aHi0, aLo1, aHi1;

#define STAGE_B(buf, k0s)                                                   \
    __builtin_amdgcn_global_load_lds((g_char*)(bsrc + (k0s)),               \
        (lds_char*)((char*)&Bs[0][0] + (buf) * (BN * BK * 2) + bofs),       \
        16, 0, 0);

#define LOAD_A(LO, HI, k0s)                                                 \
    {                                                                       \
        const float* lp = asrc + (k0s);                                     \
        LO = *(const float4*)lp;                                            \
        const float* hp = lp + (((k0s) <= hilim) ? 4 : 0);                  \
        HI = *(const float4*)hp; /* OOB-safe: k>=764 pairs with Wb==0 */    \
    }

#define WRITE_A(LO, HI, abuf)                                               \
    {                                                                       \
        u16x8 pk;                                                           \
        pk[0] = f2bf(LO.x); pk[1] = f2bf(LO.y);                             \
        pk[2] = f2bf(LO.z); pk[3] = f2bf(LO.w);                             \
        pk[4] = f2bf(HI.x); pk[5] = f2bf(HI.y);                             \
        pk[6] = f2bf(HI.z); pk[7] = f2bf(HI.w);                             \
        *(u16x8*)&As[abuf][adst] = pk;                                      \
    }

#define COMPUTE(abuf, bbuf)                                                 \
    {                                                                       \
        bf16x8 af[2], bfr[4];                                               \
        _Pragma("unroll")                                                   \
        for (int mi = 0; mi < 2; ++mi) {                                    \
            const int r = wm * 32 + mi * 16 + l16;                          \
            af[mi] = *(const bf16x8*)&As[abuf][r * BK + quad * 8];          \
        }                                                                   \
        _Pragma("unroll")                                                   \
        for (int ni = 0; ni < 4; ++ni) {                                    \
            const int r = wn * 64 + ni * 16 + l16;                          \
            bfr[ni] = *(const bf16x8*)&Bs[bbuf][r * BK + quad * 8];         \
        }                                                                   \
        __builtin_amdgcn_s_setprio(1);                                      \
        _Pragma("unroll")                                                   \
        for (int mi = 0; mi < 2; ++mi)                                      \
            _Pragma("unroll")                                               \
            for (int ni = 0; ni < 4; ++ni)                                  \
                acc[mi][ni] = __builtin_amdgcn_mfma_f32_16x16x32_bf16(      \
                    af[mi], bfr[ni], acc[mi][ni], 0, 0, 0);                 \
        __builtin_amdgcn_s_setprio(0);                                      \
    }

    // ---- prologue: tiles 0 and 1 in flight, A(0) committed to LDS ----
    STAGE_B(0, 0);                 // B(0) DMA          (1 op)
    LOAD_A(aLo0, aHi0, 0);         // A(0) regs         (2 ops)
    STAGE_B(1, BK);                // B(1) DMA          (1 op)
    LOAD_A(aLo1, aHi1, BK);        // A(1) regs         (2 ops)
    asm volatile("s_waitcnt vmcnt(3)" ::: "memory");  // A(0)+B(0) landed
    WRITE_A(aLo0, aHi0, 0);
    asm volatile("s_waitcnt lgkmcnt(0)" ::: "memory");
    __builtin_amdgcn_s_barrier();
    __builtin_amdgcn_sched_barrier(0);

    int bcur = 0;  // B(t) lives in Bs[bcur] at loop top (t even)
    for (int t = 0; t < num_k; t += 2) {
        const bool more = (t + 2 < num_k);
        const int  b1   = (bcur == 2) ? 0 : bcur + 1;   // (bcur+1)%3
        const int  b2   = (bcur == 0) ? 2 : bcur - 1;   // (bcur+2)%3

        // ---- iter t (even): set0 free, set1 holds A(t+1) ----
        if (more) {
            STAGE_B(b2, (t + 2) * BK);          // B(t+2) DMA
            LOAD_A(aLo0, aHi0, (t + 2) * BK);   // A(t+2) -> set0
        }
        COMPUTE(0, bcur);
        if (more) { asm volatile("s_waitcnt vmcnt(6)" ::: "memory"); }
        else      { asm volatile("s_waitcnt vmcnt(0)" ::: "memory"); }
        WRITE_A(aLo1, aHi1, 1);                 // A(t+1) -> As[1]
        asm volatile("s_waitcnt lgkmcnt(0)" ::: "memory");
        __builtin_amdgcn_s_barrier();
        __builtin_amdgcn_sched_barrier(0);

        // ---- iter t+1 (odd): set1 free, set0 holds A(t+2) ----
        if (more) {
            STAGE_B(bcur, (t + 3) * BK);        // B(t+3) -> Bs[(bcur+3)%3]
            LOAD_A(aLo1, aHi1, (t + 3) * BK);   // A(t+3) -> set1
        }
        COMPUTE(1, b1);
        if (more) {
            asm volatile("s_waitcnt vmcnt(6)" ::: "memory");
            WRITE_A(aLo0, aHi0, 0);             // A(t+2) -> As[0]
            asm volatile("s_waitcnt lgkmcnt(0)" ::: "memory");
        }
        __builtin_amdgcn_s_barrier();
        __builtin_amdgcn_sched_barrier(0);
        bcur = b2;
    }

    // ---- epilogue: + bias, store fp32 (col bound-checked vs 764) ----
#pragma unroll
    for (int ni = 0; ni < 4; ++ni) {
        const int col = n0 + wn * 64 + ni * 16 + l16;
        if (col < D_DIM) {
            const float bv = bias[col];
#pragma unroll
            for (int mi = 0; mi < 2; ++mi) {
                const int row = m0 + wm * 32 + mi * 16 + quad * 4;
#pragma unroll
                for (int r = 0; r < 4; ++r)
                    out[(size_t)(row + r) * D_DIM + col] = acc[mi][ni][r] + bv;
            }
        }
    }
#undef STAGE_B
#undef LOAD_A
#undef WRITE_A
#undef COMPUTE
}

extern "C" void kernel_launch(void* const* d_in, const int* in_sizes, int n_in,
                              void* d_out, int out_size, void* d_ws, size_t ws_size,
                              hipStream_t stream) {
    const float* X    = (const float*)d_in[0];
    const float* W    = (const float*)d_in[1];
    const float* bias = (const float*)d_in[2];
    float* out        = (float*)d_out;
    unsigned short* Wb = (unsigned short*)d_ws;  // DP*DP bf16 = 1.18 MB

    prep_w<<<(DP * DP) / 256, 256, 0, stream>>>(W, Wb);
    fvsbn_gemm<<<(65536 / BM) * (DP / BN), 512, 0, stream>>>(X, Wb, bias, out);
}

// Round 5
// 598.745 us; speedup vs baseline: 1.8865x; 1.8865x over previous
//
#include <hip/hip_runtime.h>

#define D_DIM 764
#define DP    768
#define BM    128
#define BN    128
#define BK    64

typedef __attribute__((ext_vector_type(8))) short bf16x8;
typedef __attribute__((ext_vector_type(8))) unsigned short u16x8;
typedef __attribute__((ext_vector_type(4))) float f32x4;

typedef __attribute__((address_space(3))) char lds_char;
typedef __attribute__((address_space(1))) const char g_char;

__device__ inline unsigned short f2bf(float f) {
    union { float f; unsigned u; } v; v.f = f;
    unsigned r = v.u + 0x7FFFu + ((v.u >> 16) & 1u);  // RNE
    return (unsigned short)(r >> 16);
}

// Mask (k < n), cast to bf16, pad to DP x DP. Layout: Wb[n][k] (BT form, K-contiguous).
__global__ void prep_w(const float* __restrict__ W, unsigned short* __restrict__ Wb) {
    int idx = blockIdx.x * blockDim.x + threadIdx.x;   // 0 .. DP*DP-1
    int n = idx / DP, k = idx - n * DP;
    float v = 0.0f;
    if (n < D_DIM && k < n) v = W[n * D_DIM + k];
    Wb[idx] = f2bf(v);
}

// X fp32 [65536][764] -> Xb bf16 [65536][768], zero-padded cols 764..767.
// One output chunk of 8 per thread; rows are 16B-aligned (764*4 = 3056 = 191*16).
__global__ void prep_x(const float* __restrict__ X, unsigned short* __restrict__ Xb) {
    int idx = blockIdx.x * blockDim.x + threadIdx.x;   // 0 .. 65536*96-1
    int r = idx / 96, c = idx - r * 96;
    const float* xp = X + (size_t)r * D_DIM + c * 8;
    float4 lo = *(const float4*)xp;                    // c*8 <= 760 always valid
    float4 hi = (c < 95) ? *(const float4*)(xp + 4)
                         : make_float4(0.f, 0.f, 0.f, 0.f);
    u16x8 pk;
    pk[0] = f2bf(lo.x); pk[1] = f2bf(lo.y); pk[2] = f2bf(lo.z); pk[3] = f2bf(lo.w);
    pk[4] = f2bf(hi.x); pk[5] = f2bf(hi.y); pk[6] = f2bf(hi.z); pk[7] = f2bf(hi.w);
    *(u16x8*)&Xb[(size_t)r * DP + c * 8] = pk;
}

// v6: no-LDS, no-barrier GEMM. Each wave owns an independent 32x64 output
// tile; A and B fragments load straight from global as bf16x8 (16 lines x
// 64 B per wave-load, every byte consumed; A L1-shared by the wn pair, Wb
// 1.18 MB L2-resident). Register double-buffer, prefetch distance 2 K-steps
// (K-step 32), compiler-counted vmcnt (never a full drain). Per-wave
// triangular skip: cols [c0,c0+63] need k < c0+64 -> num_k = (c0+64)/32,
// always even. 4 rounds of PMC showed the barrier-coupled block design
// latency-bound with all pipes <30%; this removes the coupling entirely.
__global__ __launch_bounds__(256) void fvsbn_nolds(
    const unsigned short* __restrict__ Xb,  // [65536][768] bf16
    const unsigned short* __restrict__ Wb,  // [768][768] bf16 masked
    const float* __restrict__ bias,         // [764] fp32
    float* __restrict__ out)                // [65536][764] fp32
{
    const int tid  = threadIdx.x;
    const int lane = tid & 63;
    const int wid  = tid >> 6;        // 0..3
    const int wm   = wid & 1;
    const int wn   = wid >> 1;
    const int quad = lane >> 4;
    const int l16  = lane & 15;

    // XCD-aware swizzle: 1024 m-blocks x 6 n-blocks, contiguous m per XCD.
    const int bid = blockIdx.x;       // 0..6143
    const int xcd = bid & 7;
    const int j   = bid >> 3;         // 0..767
    const int nb  = j % 6;
    const int jm  = j / 6;            // 0..127
    const int mb  = jm * 8 + xcd;     // 0..1023

    const int m0  = mb * 64 + wm * 32;        // wave's first row
    const int c0  = nb * 128 + wn * 64;       // wave's first col
    const int num_k = (c0 + 64) >> 5;         // K-steps of 32: 2,4,...,24 (even)

    const unsigned short* ap = Xb + (size_t)(m0 + l16) * DP + quad * 8;
    const unsigned short* bp = Wb + (size_t)(c0 + l16) * DP + quad * 8;

    f32x4 acc[2][4];
#pragma unroll
    for (int mi = 0; mi < 2; ++mi)
#pragma unroll
        for (int ni = 0; ni < 4; ++ni) acc[mi][ni] = (f32x4){0.f, 0.f, 0.f, 0.f};

    bf16x8 a0[2], b0[4], a1[2], b1[4];

#define LOADF(A, Bv, kk)                                                    \
    {                                                                       \
        _Pragma("unroll")                                                   \
        for (int mi = 0; mi < 2; ++mi)                                      \
            A[mi] = *(const bf16x8*)(ap + mi * 16 * DP + (kk) * 32);        \
        _Pragma("unroll")                                                   \
        for (int ni = 0; ni < 4; ++ni)                                      \
            Bv[ni] = *(const bf16x8*)(bp + ni * 16 * DP + (kk) * 32);       \
    }

#define MFMAS(A, Bv)                                                        \
    _Pragma("unroll")                                                       \
    for (int mi = 0; mi < 2; ++mi)                                          \
        _Pragma("unroll")                                                   \
        for (int ni = 0; ni < 4; ++ni)                                      \
            acc[mi][ni] = __builtin_amdgcn_mfma_f32_16x16x32_bf16(          \
                A[mi], Bv[ni], acc[mi][ni], 0, 0, 0);

    // prologue: both register sets in flight (num_k >= 2 always)
    LOADF(a0, b0, 0);
    LOADF(a1, b1, 1);

    int kk = 0;
    for (; kk + 2 < num_k; kk += 2) {
        MFMAS(a0, b0);            // waits set0 (issued 1 iter ago), set1 in flight
        LOADF(a0, b0, kk + 2);    // reuse set0 regs after consumption
        MFMAS(a1, b1);
        LOADF(a1, b1, kk + 3);    // kk+3 < num_k guaranteed (num_k even)
    }
    MFMAS(a0, b0);                // kk = num_k-2
    MFMAS(a1, b1);                // kk = num_k-1

    // epilogue: + bias, store fp32 (col bound-checked vs 764)
#pragma unroll
    for (int ni = 0; ni < 4; ++ni) {
        const int col = c0 + ni * 16 + l16;
        if (col < D_DIM) {
            const float bv = bias[col];
#pragma unroll
            for (int mi = 0; mi < 2; ++mi) {
                const int row = m0 + mi * 16 + quad * 4;
#pragma unroll
                for (int r = 0; r < 4; ++r)
                    out[(size_t)(row + r) * D_DIM + col] = acc[mi][ni][r] + bv;
            }
        }
    }
#undef LOADF
#undef MFMAS
}

// ---------------- v4 fallback (proven 178 us) if workspace too small ----------------
__global__ __launch_bounds__(512, 4) void fvsbn_gemm(
    const float* __restrict__ X,
    const unsigned short* __restrict__ Wb,
    const float* __restrict__ bias,
    float* __restrict__ out)
{
    __shared__ __align__(16) unsigned short As[2][BM * BK]; // 32 KB
    __shared__ __align__(16) unsigned short Bs[3][BN * BK]; // 48 KB

    const int tid  = threadIdx.x;
    const int lane = tid & 63;
    const int wid  = tid >> 6;
    const int wm   = wid & 3;
    const int wn   = wid >> 2;
    const int quad = lane >> 4;
    const int l16  = lane & 15;

    const int bid = blockIdx.x;
    const int xcd = bid & 7;
    const int j   = bid >> 3;
    const int nt  = j % 6;
    const int jm  = j / 6;
    const int mt  = jm * 8 + xcd;
    const int m0  = mt * BM;
    const int n0  = nt * BN;

    const int num_k = (n0 + BN) / BK;

    const unsigned short* bsrc[2];
    int bofs[2];
#pragma unroll
    for (int jj = 0; jj < 2; ++jj) {
        const int cbase = (wid * 2 + jj) * 64;
        const int c     = cbase + lane;
        const int r     = c >> 3;
        const int cc    = c & 7;
        const int g     = cc ^ (r & 7);
        bsrc[jj] = Wb + (size_t)(n0 + r) * DP + g * 8;
        bofs[jj] = cbase * 16;
    }

    const float* asrc[2];
    int adst[2], hilim[2];
#pragma unroll
    for (int i = 0; i < 2; ++i) {
        const int p  = tid + i * 512;
        const int r  = p >> 3;
        const int cc = p & 7;
        const int g  = cc ^ (r & 7);
        asrc[i]  = X + (size_t)(m0 + r) * D_DIM + g * 8;
        adst[i]  = r * BK + cc * 8;
        hilim[i] = D_DIM - 8 - g * 8;
    }

    f32x4 acc[2][4];
#pragma unroll
    for (int mi = 0; mi < 2; ++mi)
#pragma unroll
        for (int ni = 0; ni < 4; ++ni) acc[mi][ni] = (f32x4){0.f, 0.f, 0.f, 0.f};

    float4 aLo0[2], aHi0[2], aLo1[2], aHi1[2];

#define STAGE_B(buf, k0s)                                                   \
    _Pragma("unroll")                                                       \
    for (int jj = 0; jj < 2; ++jj)                                          \
        __builtin_amdgcn_global_load_lds((g_char*)(bsrc[jj] + (k0s)),       \
            (lds_char*)((char*)&Bs[0][0] + (buf) * (BN * BK * 2) + bofs[jj]),\
            16, 0, 0);

#define LOAD_A(LO, HI, k0s)                                                 \
    _Pragma("unroll")                                                       \
    for (int i = 0; i < 2; ++i) {                                           \
        const float* lp = asrc[i] + (k0s);                                  \
        LO[i] = *(const float4*)lp;                                         \
        const float* hp = lp + (((k0s) <= hilim[i]) ? 4 : 0);               \
        HI[i] = *(const float4*)hp;                                         \
    }

#define WRITE_A(LO, HI, abuf)                                               \
    _Pragma("unroll")                                                       \
    for (int i = 0; i < 2; ++i) {                                           \
        u16x8 pk;                                                           \
        pk[0] = f2bf(LO[i].x); pk[1] = f2bf(LO[i].y);                       \
        pk[2] = f2bf(LO[i].z); pk[3] = f2bf(LO[i].w);                       \
        pk[4] = f2bf(HI[i].x); pk[5] = f2bf(HI[i].y);                       \
        pk[6] = f2bf(HI[i].z); pk[7] = f2bf(HI[i].w);                       \
        *(u16x8*)&As[abuf][adst[i]] = pk;                                   \
    }

#define COMPUTE(abuf, bbuf)                                                 \
    _Pragma("unroll")                                                       \
    for (int s = 0; s < 2; ++s) {                                           \
        bf16x8 af[2], bfr[4];                                               \
        _Pragma("unroll")                                                   \
        for (int mi = 0; mi < 2; ++mi) {                                    \
            const int r = wm * 32 + mi * 16 + l16;                          \
            const int g = s * 4 + quad;                                     \
            af[mi] = *(const bf16x8*)&As[abuf][r * BK + (g ^ (r & 7)) * 8]; \
        }                                                                   \
        _Pragma("unroll")                                                   \
        for (int ni = 0; ni < 4; ++ni) {                                    \
            const int r = wn * 64 + ni * 16 + l16;                          \
            const int g = s * 4 + quad;                                     \
            bfr[ni] = *(const bf16x8*)&Bs[bbuf][r * BK + (g ^ (r & 7)) * 8];\
        }                                                                   \
        __builtin_amdgcn_s_setprio(1);                                      \
        _Pragma("unroll")                                                   \
        for (int mi = 0; mi < 2; ++mi)                                      \
            _Pragma("unroll")                                               \
            for (int ni = 0; ni < 4; ++ni)                                  \
                acc[mi][ni] = __builtin_amdgcn_mfma_f32_16x16x32_bf16(      \
                    af[mi], bfr[ni], acc[mi][ni], 0, 0, 0);                 \
        __builtin_amdgcn_s_setprio(0);                                      \
    }

    STAGE_B(0, 0);
    LOAD_A(aLo0, aHi0, 0);
    STAGE_B(1, BK);
    LOAD_A(aLo1, aHi1, BK);
    asm volatile("s_waitcnt vmcnt(6)" ::: "memory");
    WRITE_A(aLo0, aHi0, 0);
    asm volatile("s_waitcnt lgkmcnt(0)" ::: "memory");
    __builtin_amdgcn_s_barrier();
    __builtin_amdgcn_sched_barrier(0);

    int bcur = 0;
    for (int t = 0; t < num_k; t += 2) {
        const bool more = (t + 2 < num_k);
        const int  b1   = (bcur == 2) ? 0 : bcur + 1;
        const int  b2   = (bcur == 0) ? 2 : bcur - 1;

        if (more) {
            STAGE_B(b2, (t + 2) * BK);
            LOAD_A(aLo0, aHi0, (t + 2) * BK);
        }
        COMPUTE(0, bcur);
        if (more) { asm volatile("s_waitcnt vmcnt(6)" ::: "memory"); }
        else      { asm volatile("s_waitcnt vmcnt(0)" ::: "memory"); }
        WRITE_A(aLo1, aHi1, 1);
        asm volatile("s_waitcnt lgkmcnt(0)" ::: "memory");
        __builtin_amdgcn_s_barrier();
        __builtin_amdgcn_sched_barrier(0);

        if (more) {
            STAGE_B(bcur, (t + 3) * BK);
            LOAD_A(aLo1, aHi1, (t + 3) * BK);
        }
        COMPUTE(1, b1);
        if (more) {
            asm volatile("s_waitcnt vmcnt(6)" ::: "memory");
            WRITE_A(aLo0, aHi0, 0);
            asm volatile("s_waitcnt lgkmcnt(0)" ::: "memory");
        }
        __builtin_amdgcn_s_barrier();
        __builtin_amdgcn_sched_barrier(0);
        bcur = b2;
    }

#pragma unroll
    for (int ni = 0; ni < 4; ++ni) {
        const int col = n0 + wn * 64 + ni * 16 + l16;
        if (col < D_DIM) {
            const float bv = bias[col];
#pragma unroll
            for (int mi = 0; mi < 2; ++mi) {
                const int row = m0 + wm * 32 + mi * 16 + quad * 4;
#pragma unroll
                for (int r = 0; r < 4; ++r)
                    out[(size_t)(row + r) * D_DIM + col] = acc[mi][ni][r] + bv;
            }
        }
    }
#undef STAGE_B
#undef LOAD_A
#undef WRITE_A
#undef COMPUTE
}

extern "C" void kernel_launch(void* const* d_in, const int* in_sizes, int n_in,
                              void* d_out, int out_size, void* d_ws, size_t ws_size,
                              hipStream_t stream) {
    const float* X    = (const float*)d_in[0];
    const float* W    = (const float*)d_in[1];
    const float* bias = (const float*)d_in[2];
    float* out        = (float*)d_out;
    unsigned short* Wb = (unsigned short*)d_ws;           // DP*DP bf16 = 1.18 MB

    const size_t wb_bytes = (size_t)DP * DP * 2;          // 1,179,648
    const size_t xb_bytes = (size_t)65536 * DP * 2;       // 100,663,296

    prep_w<<<(DP * DP) / 256, 256, 0, stream>>>(W, Wb);

    if (ws_size >= wb_bytes + xb_bytes) {
        unsigned short* Xb = (unsigned short*)((char*)d_ws + wb_bytes);
        prep_x<<<(65536 * 96) / 256, 256, 0, stream>>>(X, Xb);
        fvsbn_nolds<<<1024 * 6, 256, 0, stream>>>(Xb, Wb, bias, out);
    } else {
        fvsbn_gemm<<<(65536 / BM) * (DP / BN), 512, 0, stream>>>(X, Wb, bias, out);
    }
}